// Round 4
// baseline (182.369 us; speedup 1.0000x reference)
//
#include <hip/hip_runtime.h>
#include <hip/hip_bf16.h>

typedef __attribute__((ext_vector_type(8))) short short8;
typedef __attribute__((ext_vector_type(4))) float f32x4;

#define DIM_D 256
#define DIM_O 256
#define DIM_K 8
#define BM 128
#define DCHUNK 16
#define NCHUNK (DIM_D / DCHUNK)   // 16

__device__ __forceinline__ unsigned short f2bf(float f) {
    union { float f; unsigned int u; } v; v.f = f;
    unsigned int u = v.u;
    u += 0x7fffu + ((u >> 16) & 1u);   // round-to-nearest-even
    return (unsigned short)(u >> 16);
}

// v_cvt_pk_bf16_f32: dst.lo = bf16(lo), dst.hi = bf16(hi), RNE — 1 instr
__device__ __forceinline__ unsigned int cvt_pk_bf16(float lo, float hi) {
    unsigned int r;
    asm("v_cvt_pk_bf16_f32 %0, %1, %2" : "=v"(r) : "v"(lo), "v"(hi));
    return r;
}

// Pack cheby_coeffs (O, D, K) f32 -> W_packed bf16 in MFMA B-fragment order:
// wp[ksg][F][lane][j] = c[o = 16F + (lane&15)][d = ksg*4 + (lane>>4)][k = j]
__global__ void pack_w_kernel(const float* __restrict__ coeffs,
                              unsigned short* __restrict__ wp) {
    int e = blockIdx.x * 256 + threadIdx.x;      // 0 .. 524287
    int j   = e & 7;
    int l   = (e >> 3) & 63;
    int F   = (e >> 9) & 15;
    int ksg = e >> 13;                           // 0..63
    int o = F * 16 + (l & 15);
    int d = ksg * 4 + (l >> 4);
    wp[e] = f2bf(coeffs[(size_t)(o * DIM_D + d) * DIM_K + j]);
}

// tanh + Chebyshev recurrence + packed-bf16 + swizzled LDS write (8 elems)
__device__ __forceinline__ void cheb_pack8(const float xv[8],
                                           unsigned short* dst_row,
                                           int lrow, int dpart) {
    #pragma unroll
    for (int i = 0; i < 8; ++i) {
        // tanh(x) = 1 - 2/(e^{2x}+1); |x| <= ~6 for randn inputs, no clamp
        float e2 = __expf(2.f * xv[i]);
        float r  = __builtin_amdgcn_rcpf(e2 + 1.f);
        float T1 = __builtin_fmaf(-2.f, r, 1.f);
        float tx = T1 + T1;
        float T2 = __builtin_fmaf(tx, T1, -1.f);
        float T3 = __builtin_fmaf(tx, T2, -T1);
        float T4 = __builtin_fmaf(tx, T3, -T2);
        float T5 = __builtin_fmaf(tx, T4, -T3);
        float T6 = __builtin_fmaf(tx, T5, -T4);
        float T7 = __builtin_fmaf(tx, T6, -T5);
        union { unsigned int u[4]; short8 s; } tv;
        tv.u[0] = cvt_pk_bf16(1.f, T1);
        tv.u[1] = cvt_pk_bf16(T2, T3);
        tv.u[2] = cvt_pk_bf16(T4, T5);
        tv.u[3] = cvt_pk_bf16(T6, T7);
        int slot = (dpart + i) ^ (lrow & 15);
        *(short8*)(dst_row + slot * 8) = tv.s;
    }
}

__global__ __launch_bounds__(512, 2) void cfkan_kernel(
    const float* __restrict__ x,
    const unsigned short* __restrict__ wp,
    const float* __restrict__ bias,
    float* __restrict__ y)
{
    // double-buffered A tile, XOR-swizzled slots (slot = d ^ (row&15)); 64 KB
    __shared__ unsigned short Abuf[2][BM][16 * 8];

    const int t = threadIdx.x;
    const int wid = t >> 6;          // 0..7; 0-3 = MFMA consumers, 4-7 = producers
    const int l = t & 63;
    const int row0 = blockIdx.x * BM;
    const short8* wp8 = (const short8*)wp;
    const bool is_cons = (wid < 4);

    // ---- consumer state ----
    f32x4 acc[8][4];
    short8 bA[2][4];                 // prefetched B frags: ks0-1 of current chunk

    // ---- producer state ----
    const int pt    = t & 255;       // producer thread 0..255
    const int lrow  = pt >> 1;       // row staged (0..127)
    const int dpart = (pt & 1) * 8;  // which 8 of the 16 chunk-d's
    const float* xrow = x + (size_t)(row0 + lrow) * DIM_D + dpart;

    // ---- prologue ----
    if (is_cons) {
        #pragma unroll
        for (int r = 0; r < 8; ++r)
            #pragma unroll
            for (int f = 0; f < 4; ++f)
                acc[r][f] = (f32x4){0.f, 0.f, 0.f, 0.f};
        // prefetch chunk 0, ks0-1 B fragments
        #pragma unroll
        for (int ks = 0; ks < 2; ++ks)
            #pragma unroll
            for (int f = 0; f < 4; ++f)
                bA[ks][f] = wp8[(ks * 16 + wid * 4 + f) * 64 + l];
    } else {
        float4 v0 = *(const float4*)xrow;
        float4 v1 = *(const float4*)(xrow + 4);
        float xv[8] = {v0.x, v0.y, v0.z, v0.w, v1.x, v1.y, v1.z, v1.w};
        cheb_pack8(xv, &Abuf[0][lrow][0], lrow, dpart);
    }
    __syncthreads();

    // ---- main loop: one barrier per chunk-period ----
    #pragma unroll 1
    for (int c = 0; c < NCHUNK; ++c) {
        if (is_cons) {
            const unsigned short (*A)[16 * 8] = Abuf[c & 1];
            // issue bB loads (ks2-3 of chunk c) — consumed ~1.2k cyc later
            short8 bB[2][4];
            #pragma unroll
            for (int ks = 0; ks < 2; ++ks)
                #pragma unroll
                for (int f = 0; f < 4; ++f)
                    bB[ks][f] = wp8[((c * 4 + 2 + ks) * 16 + wid * 4 + f) * 64 + l];

            __builtin_amdgcn_s_setprio(1);
            #pragma unroll
            for (int ks = 0; ks < 2; ++ks) {
                const int slot = (ks * 4 + (l >> 4)) ^ (l & 15);
                #pragma unroll
                for (int r = 0; r < 8; ++r) {
                    short8 a = *(const short8*)(&A[r * 16 + (l & 15)][0] + slot * 8);
                    #pragma unroll
                    for (int f = 0; f < 4; ++f)
                        acc[r][f] = __builtin_amdgcn_mfma_f32_16x16x32_bf16(
                            a, bA[ks][f], acc[r][f], 0, 0, 0);
                }
            }
            __builtin_amdgcn_s_setprio(0);

            // prefetch next chunk's ks0-1 (completes by the barrier drain — free)
            if (c < NCHUNK - 1) {
                #pragma unroll
                for (int ks = 0; ks < 2; ++ks)
                    #pragma unroll
                    for (int f = 0; f < 4; ++f)
                        bA[ks][f] = wp8[(((c + 1) * 4 + ks) * 16 + wid * 4 + f) * 64 + l];
            }

            __builtin_amdgcn_s_setprio(1);
            #pragma unroll
            for (int ks = 2; ks < 4; ++ks) {
                const int slot = (ks * 4 + (l >> 4)) ^ (l & 15);
                #pragma unroll
                for (int r = 0; r < 8; ++r) {
                    short8 a = *(const short8*)(&A[r * 16 + (l & 15)][0] + slot * 8);
                    #pragma unroll
                    for (int f = 0; f < 4; ++f)
                        acc[r][f] = __builtin_amdgcn_mfma_f32_16x16x32_bf16(
                            a, bB[ks - 2][f], acc[r][f], 0, 0, 0);
                }
            }
            __builtin_amdgcn_s_setprio(0);
        } else {
            if (c < NCHUNK - 1) {
                float4 v0 = *(const float4*)(xrow + (c + 1) * DCHUNK);
                float4 v1 = *(const float4*)(xrow + (c + 1) * DCHUNK + 4);
                float xv[8] = {v0.x, v0.y, v0.z, v0.w, v1.x, v1.y, v1.z, v1.w};
                cheb_pack8(xv, &Abuf[(c + 1) & 1][lrow][0], lrow, dpart);
            }
        }
        __syncthreads();
    }

    // ---- epilogue (consumers only): add bias, store f32 ----
    if (is_cons) {
        #pragma unroll
        for (int f = 0; f < 4; ++f) {
            const int col = wid * 64 + f * 16 + (l & 15);
            const float bv = bias[col];
            #pragma unroll
            for (int r = 0; r < 8; ++r) {
                const int grow = row0 + r * 16 + (l >> 4) * 4;
                #pragma unroll
                for (int q = 0; q < 4; ++q)
                    y[(size_t)(grow + q) * DIM_O + col] = acc[r][f][q] + bv;
            }
        }
    }
}

extern "C" void kernel_launch(void* const* d_in, const int* in_sizes, int n_in,
                              void* d_out, int out_size, void* d_ws, size_t ws_size,
                              hipStream_t stream) {
    const float* x      = (const float*)d_in[0];
    const float* coeffs = (const float*)d_in[1];
    const float* bias   = (const float*)d_in[2];
    float* y = (float*)d_out;
    unsigned short* wp = (unsigned short*)d_ws;   // 2048*256 bf16 = 1 MB

    const int n_tokens = in_sizes[0] / DIM_D;     // 65536

    pack_w_kernel<<<(DIM_O * DIM_D * DIM_K) / 256, 256, 0, stream>>>(coeffs, wp);
    cfkan_kernel<<<n_tokens / BM, 512, 0, stream>>>(x, wp, bias, y);
}

// Round 5
// 77.090 us; speedup vs baseline: 2.3657x; 2.3657x over previous
//
#include <hip/hip_runtime.h>
#include <hip/hip_bf16.h>

typedef __attribute__((ext_vector_type(8))) short short8;
typedef __attribute__((ext_vector_type(4))) float f32x4;

#define DIM_D 256
#define DIM_O 256
#define DIM_K 8
#define BM 128
#define DCHUNK 16
#define NCHUNK (DIM_D / DCHUNK)   // 16

__device__ __forceinline__ unsigned short f2bf(float f) {
    union { float f; unsigned int u; } v; v.f = f;
    unsigned int u = v.u;
    u += 0x7fffu + ((u >> 16) & 1u);   // round-to-nearest-even
    return (unsigned short)(u >> 16);
}

// v_cvt_pk_bf16_f32: dst.lo = bf16(lo), dst.hi = bf16(hi), RNE — 1 instr
__device__ __forceinline__ unsigned int cvt_pk_bf16(float lo, float hi) {
    unsigned int r;
    asm("v_cvt_pk_bf16_f32 %0, %1, %2" : "=v"(r) : "v"(lo), "v"(hi));
    return r;
}

// Pack cheby_coeffs (O, D, K) f32 -> W_packed bf16 in MFMA B-fragment order:
// wp[ksg][F][lane][j] = c[o = 16F + (lane&15)][d = ksg*4 + (lane>>4)][k = j]
__global__ void pack_w_kernel(const float* __restrict__ coeffs,
                              unsigned short* __restrict__ wp) {
    int e = blockIdx.x * 256 + threadIdx.x;      // 0 .. 524287
    int j   = e & 7;
    int l   = (e >> 3) & 63;
    int F   = (e >> 9) & 15;
    int ksg = e >> 13;                           // 0..63
    int o = F * 16 + (l & 15);
    int d = ksg * 4 + (l >> 4);
    wp[e] = f2bf(coeffs[(size_t)(o * DIM_D + d) * DIM_K + j]);
}

// tanh + Chebyshev recurrence + packed-bf16 + swizzled LDS write (8 elems)
__device__ __forceinline__ void cheb_pack8(const float xv[8],
                                           unsigned short* dst_row,
                                           int lrow, int dpart) {
    #pragma unroll
    for (int i = 0; i < 8; ++i) {
        // tanh(x) = 1 - 2/(e^{2x}+1); |x| <= ~6 for randn inputs, no clamp
        float e2 = __expf(2.f * xv[i]);
        float r  = __builtin_amdgcn_rcpf(e2 + 1.f);
        float T1 = __builtin_fmaf(-2.f, r, 1.f);
        float tx = T1 + T1;
        float T2 = __builtin_fmaf(tx, T1, -1.f);
        float T3 = __builtin_fmaf(tx, T2, -T1);
        float T4 = __builtin_fmaf(tx, T3, -T2);
        float T5 = __builtin_fmaf(tx, T4, -T3);
        float T6 = __builtin_fmaf(tx, T5, -T4);
        float T7 = __builtin_fmaf(tx, T6, -T5);
        union { unsigned int u[4]; short8 s; } tv;
        tv.u[0] = cvt_pk_bf16(1.f, T1);
        tv.u[1] = cvt_pk_bf16(T2, T3);
        tv.u[2] = cvt_pk_bf16(T4, T5);
        tv.u[3] = cvt_pk_bf16(T6, T7);
        int slot = (dpart + i) ^ (lrow & 15);
        *(short8*)(dst_row + slot * 8) = tv.s;
    }
}

// one chunk's MFMA work: 4 k-steps (K=32 each); ks0 B-frags come prefetched
__device__ __forceinline__ void mfma_chunk(const unsigned short (*A)[16 * 8],
                                           const short8* __restrict__ wp8,
                                           int c, int w, int l,
                                           const short8 bA[4],
                                           f32x4 acc[8][4]) {
    __builtin_amdgcn_s_setprio(1);
    #pragma unroll
    for (int ks = 0; ks < 4; ++ks) {
        const int ksg = c * 4 + ks;
        short8 b[4];
        #pragma unroll
        for (int f = 0; f < 4; ++f)
            b[f] = (ks == 0) ? bA[f]
                             : wp8[(ksg * 16 + w * 4 + f) * 64 + l];
        const int slot = (ks * 4 + (l >> 4)) ^ (l & 15);
        #pragma unroll
        for (int r = 0; r < 8; ++r) {
            short8 a = *(const short8*)(&A[r * 16 + (l & 15)][0] + slot * 8);
            #pragma unroll
            for (int f = 0; f < 4; ++f)
                acc[r][f] = __builtin_amdgcn_mfma_f32_16x16x32_bf16(
                    a, b[f], acc[r][f], 0, 0, 0);
        }
    }
    __builtin_amdgcn_s_setprio(0);
}

__global__ __launch_bounds__(256, 2) void cfkan_kernel(
    const float* __restrict__ x,
    const unsigned short* __restrict__ wp,
    const float* __restrict__ bias,
    float* __restrict__ y)
{
    // double-buffered A tile, XOR-swizzled slots (slot = d ^ (row&15)); 64 KB
    __shared__ unsigned short Abuf[2][BM][16 * 8];

    const int t = threadIdx.x;
    const int w = t >> 6;            // wave 0..3 -> output cols [64w, 64w+64)
    const int l = t & 63;
    const int row0 = blockIdx.x * BM;
    const short8* wp8 = (const short8*)wp;

    f32x4 acc[8][4];
    #pragma unroll
    for (int r = 0; r < 8; ++r)
        #pragma unroll
        for (int f = 0; f < 4; ++f)
            acc[r][f] = (f32x4){0.f, 0.f, 0.f, 0.f};

    const int lrow  = t >> 1;        // 0..127 (row this thread stages)
    const int dpart = (t & 1) * 8;   // which 8 of the 16 chunk-d's
    const float* xrow = x + (size_t)(row0 + lrow) * DIM_D + dpart;

    // ---- prologue: pack chunk 0 now; preload x(chunk1) + B(chunk0,ks0) ----
    {
        float4 v0 = *(const float4*)xrow;
        float4 v1 = *(const float4*)(xrow + 4);
        float xv[8] = {v0.x, v0.y, v0.z, v0.w, v1.x, v1.y, v1.z, v1.w};
        cheb_pack8(xv, &Abuf[0][lrow][0], lrow, dpart);
    }
    float4 vA0 = *(const float4*)(xrow + DCHUNK);
    float4 vA1 = *(const float4*)(xrow + DCHUNK + 4);
    short8 bA[4];
    #pragma unroll
    for (int f = 0; f < 4; ++f)
        bA[f] = wp8[(w * 4 + f) * 64 + l];
    __syncthreads();

    // ---- main loop: one barrier per chunk; wave-parity phase order ----
    #pragma unroll 1
    for (int c = 0; c < NCHUNK - 1; ++c) {
        const int buf = c & 1;
        // issue x loads for chunk c+2 early (consumed next iteration)
        float4 vB0, vB1;
        if (c + 2 < NCHUNK) {
            vB0 = *(const float4*)(xrow + (c + 2) * DCHUNK);
            vB1 = *(const float4*)(xrow + (c + 2) * DCHUNK + 4);
        }
        float xv[8] = {vA0.x, vA0.y, vA0.z, vA0.w, vA1.x, vA1.y, vA1.z, vA1.w};

        if ((w & 1) == 0) {
            mfma_chunk(Abuf[buf], wp8, c, w, l, bA, acc);
            cheb_pack8(xv, &Abuf[buf ^ 1][lrow][0], lrow, dpart);
        } else {
            cheb_pack8(xv, &Abuf[buf ^ 1][lrow][0], lrow, dpart);
            mfma_chunk(Abuf[buf], wp8, c, w, l, bA, acc);
        }

        // prefetch next chunk's ks0 B-frags; loads stay in flight across barrier
        #pragma unroll
        for (int f = 0; f < 4; ++f)
            bA[f] = wp8[(((c + 1) * 4) * 16 + w * 4 + f) * 64 + l];
        vA0 = vB0; vA1 = vB1;
        __syncthreads();
    }
    mfma_chunk(Abuf[(NCHUNK - 1) & 1], wp8, NCHUNK - 1, w, l, bA, acc);

    // ---- epilogue: add bias, store f32 ----
    #pragma unroll
    for (int f = 0; f < 4; ++f) {
        const int col = w * 64 + f * 16 + (l & 15);
        const float bv = bias[col];
        #pragma unroll
        for (int r = 0; r < 8; ++r) {
            const int grow = row0 + r * 16 + (l >> 4) * 4;
            #pragma unroll
            for (int q = 0; q < 4; ++q)
                y[(size_t)(grow + q) * DIM_O + col] = acc[r][f][q] + bv;
        }
    }
}

extern "C" void kernel_launch(void* const* d_in, const int* in_sizes, int n_in,
                              void* d_out, int out_size, void* d_ws, size_t ws_size,
                              hipStream_t stream) {
    const float* x      = (const float*)d_in[0];
    const float* coeffs = (const float*)d_in[1];
    const float* bias   = (const float*)d_in[2];
    float* y = (float*)d_out;
    unsigned short* wp = (unsigned short*)d_ws;   // 2048*256 bf16 = 1 MB

    const int n_tokens = in_sizes[0] / DIM_D;     // 65536

    pack_w_kernel<<<(DIM_O * DIM_D * DIM_K) / 256, 256, 0, stream>>>(coeffs, wp);
    cfkan_kernel<<<n_tokens / BM, 256, 0, stream>>>(x, wp, bias, y);
}